// Round 3
// baseline (97.001 us; speedup 1.0000x reference)
//
#include <hip/hip_runtime.h>
#include <cmath>

constexpr int NN    = 1536;  // nodes
constexpr int FF    = 512;   // in features
constexpr int HH    = 64;    // hidden
constexpr int RPB   = 6;     // rows per block
constexpr int NB    = NN / RPB;  // 256 blocks = 1 per CU
constexpr int NT    = 512;   // 8 waves
constexpr int WAVES = NT / 64;

struct Params {
  const float *x, *adj, *W1, *b1, *W2, *b2, *W3, *b3;
  float *t1, *B2, *B3, *out;
  unsigned* bar;
};

__device__ __forceinline__ void grid_barrier(unsigned* bar, int slot) {
  __syncthreads();
  if (threadIdx.x == 0) {
    unsigned* c = bar + slot * 32;  // one cache line per barrier slot
    __hip_atomic_fetch_add(c, 1u, __ATOMIC_RELEASE, __HIP_MEMORY_SCOPE_AGENT);
    while (__hip_atomic_load(c, __ATOMIC_ACQUIRE, __HIP_MEMORY_SCOPE_AGENT) <
           (unsigned)NB)
      __builtin_amdgcn_s_sleep(2);
  }
  __syncthreads();
}

__device__ __forceinline__ void wave_reduce_g4(float4& v) {
  v.x += __shfl_xor(v.x, 16, 64); v.y += __shfl_xor(v.y, 16, 64);
  v.z += __shfl_xor(v.z, 16, 64); v.w += __shfl_xor(v.w, 16, 64);
  v.x += __shfl_xor(v.x, 32, 64); v.y += __shfl_xor(v.y, 32, 64);
  v.z += __shfl_xor(v.z, 32, 64); v.w += __shfl_xor(v.w, 32, 64);
}

__global__ __launch_bounds__(NT) void gcn_fused(Params p) {
  __shared__ float arow[RPB * NN];               // 36 KB, staged ONCE
  __shared__ float xr[RPB * FF];                 // 12 KB (phase 0 only)
  __shared__ float Wl[2 * HH * HH];              // 32 KB (W2, then W3)
  __shared__ float red[WAVES][RPB][HH];          // 12 KB
  __shared__ float xloc[RPB][HH];                // activations
  __shared__ float anext[RPB][HH];               // block-local A = x@W_top
  __shared__ float degs[RPB];

  const int tid = threadIdx.x, lane = tid & 63, wave = tid >> 6;
  const int i0 = blockIdx.x * RPB;
  const int g4 = lane >> 4, c4 = (lane & 15) * 4;

  // ---- stage everything this block reuses: x rows, adj slab, W2 ----
  {
    const float4* src = (const float4*)(p.x + (size_t)i0 * FF);
    float4* dst = (float4*)xr;
    for (int idx = tid; idx < RPB * FF / 4; idx += NT) dst[idx] = src[idx];
  }
  {
    const float4* src = (const float4*)(p.adj + (size_t)i0 * NN);
    float4* dst = (float4*)arow;
    for (int idx = tid; idx < RPB * NN / 4; idx += NT) dst[idx] = src[idx];
  }
  {
    const float4* src = (const float4*)p.W2;
    float4* dst = (float4*)Wl;
    for (int idx = tid; idx < 2 * HH * HH / 4; idx += NT) dst[idx] = src[idx];
  }
  __syncthreads();

  // deg = rowsum(adj), once
  if (wave < RPB) {
    float v = 0.f;
    for (int j = lane; j < NN; j += 64) v += arow[wave * NN + j];
#pragma unroll
    for (int off = 32; off; off >>= 1) v += __shfl_xor(v, off, 64);
    if (lane == 0) degs[wave] = v;
  }

  // ---- phase 0: t1 = x @ W1 ----
  {
    float4 acc[RPB];
#pragma unroll
    for (int r = 0; r < RPB; ++r) acc[r] = make_float4(0.f, 0.f, 0.f, 0.f);
    const int jbeg = wave * (FF / WAVES);
#pragma unroll 4
    for (int j = jbeg; j < jbeg + FF / WAVES; j += 4) {
      float4 t = *(const float4*)(p.W1 + (size_t)(j + g4) * HH + c4);
#pragma unroll
      for (int r = 0; r < RPB; ++r) {
        float a = xr[r * FF + j + g4];
        acc[r].x = fmaf(a, t.x, acc[r].x);
        acc[r].y = fmaf(a, t.y, acc[r].y);
        acc[r].z = fmaf(a, t.z, acc[r].z);
        acc[r].w = fmaf(a, t.w, acc[r].w);
      }
    }
#pragma unroll
    for (int r = 0; r < RPB; ++r) {
      wave_reduce_g4(acc[r]);
      if (lane < 16) *(float4*)&red[wave][r][lane * 4] = acc[r];
    }
    __syncthreads();
    if (tid < RPB * HH) {
      int r = tid >> 6, c = tid & 63;
      float v = 0.f;
#pragma unroll
      for (int w = 0; w < WAVES; ++w) v += red[w][r][c];
      p.t1[(size_t)(i0 + r) * HH + c] = v;
    }
  }
  grid_barrier(p.bar, 0);

  // ---- phases 1..3: x = act(adj@T [+ anext*deg] + b); A,B = x @ Wn ----
#pragma unroll 1
  for (int layer = 0; layer < 3; ++layer) {
    const float* T   = layer == 0 ? p.t1 : (layer == 1 ? p.B2 : p.B3);
    const float* bia = layer == 0 ? p.b1 : (layer == 1 ? p.b2 : p.b3);
    float* Bout      = layer == 0 ? p.B2 : p.B3;

    if (layer == 1) {  // swap W2 -> W3 (old Wl fully consumed pre-barrier)
      const float4* src = (const float4*)p.W3;
      float4* dst = (float4*)Wl;
      for (int idx = tid; idx < 2 * HH * HH / 4; idx += NT) dst[idx] = src[idx];
    }

    float4 acc[RPB];
#pragma unroll
    for (int r = 0; r < RPB; ++r) acc[r] = make_float4(0.f, 0.f, 0.f, 0.f);
    const int jbeg = wave * (NN / WAVES);  // 192 j per wave
#pragma unroll 4
    for (int j = jbeg; j < jbeg + NN / WAVES; j += 4) {
      float4 t = *(const float4*)(T + (size_t)(j + g4) * HH + c4);
#pragma unroll
      for (int r = 0; r < RPB; ++r) {
        float a = arow[r * NN + j + g4];
        acc[r].x = fmaf(a, t.x, acc[r].x);
        acc[r].y = fmaf(a, t.y, acc[r].y);
        acc[r].z = fmaf(a, t.z, acc[r].z);
        acc[r].w = fmaf(a, t.w, acc[r].w);
      }
    }
#pragma unroll
    for (int r = 0; r < RPB; ++r) {
      wave_reduce_g4(acc[r]);
      if (lane < 16) *(float4*)&red[wave][r][lane * 4] = acc[r];
    }
    __syncthreads();

    // combine + bias + deg-term + activation
    if (tid < RPB * HH) {
      int r = tid >> 6, c = tid & 63;
      float v = bia[c];
#pragma unroll
      for (int w = 0; w < WAVES; ++w) v += red[w][r][c];
      if (layer >= 1) v += anext[r][c] * degs[r];
      if (layer == 0) v = fmaxf(v, 0.f);
      if (layer == 1) v = v > 0.f ? v : expm1f(v);
      xloc[r][c] = v;
    }
    __syncthreads();

    if (layer < 2) {
      // A_next (LDS) = x @ Wn[:64];  B_next (global) = x @ Wn[64:]
      for (int idx = tid; idx < RPB * 2 * HH; idx += NT) {
        int r = idx >> 7, cc = idx & 127;
        int half = cc >> 6, col = cc & 63;
        float s = 0.f;
#pragma unroll
        for (int k = 0; k < HH; ++k)
          s = fmaf(xloc[r][k], Wl[(half * HH + k) * HH + col], s);
        if (half) Bout[(size_t)(i0 + r) * HH + col] = s;
        else anext[r][col] = s;
      }
      grid_barrier(p.bar, 1 + layer);
    } else {
      // log_softmax per row (one wave per row)
      if (wave < RPB) {
        float v = xloc[wave][lane];
        float m = v;
#pragma unroll
        for (int off = 32; off; off >>= 1)
          m = fmaxf(m, __shfl_xor(m, off, 64));
        float e = expf(v - m);
        float s = e;
#pragma unroll
        for (int off = 32; off; off >>= 1) s += __shfl_xor(s, off, 64);
        p.out[(size_t)(i0 + wave) * HH + lane] = v - m - logf(s);
      }
    }
  }
}

extern "C" void kernel_launch(void* const* d_in, const int* in_sizes, int n_in,
                              void* d_out, int out_size, void* d_ws,
                              size_t ws_size, hipStream_t stream) {
  Params p;
  p.x   = (const float*)d_in[0];
  p.adj = (const float*)d_in[2];   // adj1; d_in[1]/d_in[3] are dead inputs
  p.W1  = (const float*)d_in[4];
  p.b1  = (const float*)d_in[5];
  p.W2  = (const float*)d_in[6];
  p.b2  = (const float*)d_in[7];
  p.W3  = (const float*)d_in[8];
  p.b3  = (const float*)d_in[9];
  p.out = (float*)d_out;

  float* ws = (float*)d_ws;
  p.t1 = ws;                   // [1536,64]
  p.B2 = ws + 1 * NN * HH;
  p.B3 = ws + 2 * NN * HH;
  p.bar = (unsigned*)(ws + 3 * NN * HH);

  // barrier slots must start at 0 every call (harness poisons ws once only)
  hipMemsetAsync((void*)p.bar, 0, 3 * 32 * sizeof(unsigned), stream);

  void* args[] = {&p};
  hipLaunchCooperativeKernel((const void*)gcn_fused, dim3(NB), dim3(NT), args,
                             0, stream);
}

// Round 4
// 43.248 us; speedup vs baseline: 2.2429x; 2.2429x over previous
//
#include <hip/hip_runtime.h>
#include <cmath>

constexpr int NN    = 1536;  // nodes
constexpr int FF    = 512;   // in features
constexpr int HH    = 64;    // hidden
constexpr int RPB   = 6;     // rows per block
constexpr int NB    = NN / RPB;  // 256 blocks = 1 per CU
constexpr int NT    = 1024;  // 16 waves -> 4 waves/SIMD for latency hiding
constexpr int WAVES = NT / 64;

__device__ __forceinline__ void wave_reduce_g4(float4& v) {
  // sum across the 4 lane-groups (lane>>4): xor 16, then 32
  v.x += __shfl_xor(v.x, 16, 64); v.y += __shfl_xor(v.y, 16, 64);
  v.z += __shfl_xor(v.z, 16, 64); v.w += __shfl_xor(v.w, 16, 64);
  v.x += __shfl_xor(v.x, 32, 64); v.y += __shfl_xor(v.y, 32, 64);
  v.z += __shfl_xor(v.z, 32, 64); v.w += __shfl_xor(v.w, 32, 64);
}

// t1 = x_init @ W1   ([1536,512] @ [512,64])
__global__ __launch_bounds__(NT, 4) void k_xw1(const float* __restrict__ x,
                                               const float* __restrict__ W,
                                               float* __restrict__ out) {
  __shared__ float xr[RPB * FF];                // 12 KB
  __shared__ float red[WAVES][RPB][HH];         // 24 KB
  const int tid = threadIdx.x;
  const int i0 = blockIdx.x * RPB;
  const int lane = tid & 63, wave = tid >> 6;

  {
    const float4* src = (const float4*)(x + (size_t)i0 * FF);
    float4* dst = (float4*)xr;
    for (int idx = tid; idx < RPB * FF / 4; idx += NT) dst[idx] = src[idx];
  }
  __syncthreads();

  const int g4 = lane >> 4, c4 = (lane & 15) * 4;
  float4 acc[RPB];
#pragma unroll
  for (int r = 0; r < RPB; ++r) acc[r] = make_float4(0.f, 0.f, 0.f, 0.f);

  const int jbeg = wave * (FF / WAVES);  // 32 j per wave
#pragma unroll 8
  for (int j = jbeg; j < jbeg + FF / WAVES; j += 4) {
    float4 t = *(const float4*)(W + (size_t)(j + g4) * HH + c4);
#pragma unroll
    for (int r = 0; r < RPB; ++r) {
      float a = xr[r * FF + j + g4];
      acc[r].x = fmaf(a, t.x, acc[r].x);
      acc[r].y = fmaf(a, t.y, acc[r].y);
      acc[r].z = fmaf(a, t.z, acc[r].z);
      acc[r].w = fmaf(a, t.w, acc[r].w);
    }
  }
#pragma unroll
  for (int r = 0; r < RPB; ++r) {
    wave_reduce_g4(acc[r]);
    if (lane < 16) *(float4*)&red[wave][r][lane * 4] = acc[r];
  }
  __syncthreads();

  if (tid < RPB * HH) {
    int r = tid >> 6, c = tid & 63;
    float v = 0.f;
#pragma unroll
    for (int w = 0; w < WAVES; ++w) v += red[w][r][c];
    out[(size_t)(i0 + r) * HH + c] = v;
  }
}

// MODE 0: x = relu(adj@T + b);            outA/outB = x @ Wn halves
// MODE 1: x = elu(Ain*deg + adj@T + b);   outA/outB = x @ Wn halves
// MODE 2: x = Ain*deg + adj@T + b;        outA = log_softmax(x, rows)
template <int MODE>
__global__ __launch_bounds__(NT, 4) void k_layer(
    const float* __restrict__ adj, const float* __restrict__ T,
    const float* __restrict__ Ain, const float* __restrict__ bias,
    const float* __restrict__ Wn,
    float* __restrict__ outA, float* __restrict__ outB) {
  __shared__ float arow[RPB * NN];              // 36 KB
  __shared__ float red[WAVES][RPB][HH];         // 24 KB
  __shared__ float xloc[RPB][HH];               // 1.5 KB
  __shared__ float Wl[2 * HH * HH];             // 32 KB (MODE<2)
  __shared__ float degs[RPB];
  const int tid = threadIdx.x;
  const int i0 = blockIdx.x * RPB;
  const int lane = tid & 63, wave = tid >> 6;

  // stage the 6-row adj slab (contiguous in global)
  {
    const float4* src = (const float4*)(adj + (size_t)i0 * NN);
    float4* dst = (float4*)arow;
    for (int idx = tid; idx < RPB * NN / 4; idx += NT) dst[idx] = src[idx];
  }
  if (MODE < 2) {
    const float4* src = (const float4*)Wn;
    float4* dst = (float4*)Wl;
    for (int idx = tid; idx < 2 * HH * HH / 4; idx += NT) dst[idx] = src[idx];
  }
  __syncthreads();

  // deg = rowsum(adj row), one wave per row, from LDS
  if (MODE >= 1 && wave < RPB) {
    float v = 0.f;
    for (int j = lane; j < NN; j += 64) v += arow[wave * NN + j];
#pragma unroll
    for (int off = 32; off; off >>= 1) v += __shfl_xor(v, off, 64);
    if (lane == 0) degs[wave] = v;
  }

  // adj @ T: wave w covers 96 j; lane loads float4 of T (coalesced 1KB/wave)
  const int g4 = lane >> 4, c4 = (lane & 15) * 4;
  float4 acc[RPB];
#pragma unroll
  for (int r = 0; r < RPB; ++r) acc[r] = make_float4(0.f, 0.f, 0.f, 0.f);

  const int jbeg = wave * (NN / WAVES);  // 96 j per wave
#pragma unroll 8
  for (int j = jbeg; j < jbeg + NN / WAVES; j += 4) {
    float4 t = *(const float4*)(T + (size_t)(j + g4) * HH + c4);
#pragma unroll
    for (int r = 0; r < RPB; ++r) {
      float a = arow[r * NN + j + g4];
      acc[r].x = fmaf(a, t.x, acc[r].x);
      acc[r].y = fmaf(a, t.y, acc[r].y);
      acc[r].z = fmaf(a, t.z, acc[r].z);
      acc[r].w = fmaf(a, t.w, acc[r].w);
    }
  }
#pragma unroll
  for (int r = 0; r < RPB; ++r) {
    wave_reduce_g4(acc[r]);
    if (lane < 16) *(float4*)&red[wave][r][lane * 4] = acc[r];
  }
  __syncthreads();

  // combine waves + bias + deg term + activation
  if (tid < RPB * HH) {
    int r = tid >> 6, c = tid & 63;
    float v = bias[c];
#pragma unroll
    for (int w = 0; w < WAVES; ++w) v += red[w][r][c];
    if (MODE >= 1) v += Ain[(size_t)(i0 + r) * HH + c] * degs[r];
    if (MODE == 0) v = fmaxf(v, 0.f);
    if (MODE == 1) v = v > 0.f ? v : expm1f(v);
    xloc[r][c] = v;
  }
  __syncthreads();

  if (MODE < 2) {
    // next layer's A = x @ Wn[:64], B = x @ Wn[64:]
    for (int idx = tid; idx < RPB * 2 * HH; idx += NT) {
      int r = idx >> 7, cc = idx & 127;
      int half = cc >> 6, col = cc & 63;
      float s = 0.f;
#pragma unroll
      for (int k = 0; k < HH; ++k)
        s = fmaf(xloc[r][k], Wl[(half * HH + k) * HH + col], s);
      (half ? outB : outA)[(size_t)(i0 + r) * HH + col] = s;
    }
  } else {
    // log_softmax per row (one wave per row)
    if (wave < RPB) {
      float v = xloc[wave][lane];
      float m = v;
#pragma unroll
      for (int off = 32; off; off >>= 1) m = fmaxf(m, __shfl_xor(m, off, 64));
      float e = expf(v - m);
      float s = e;
#pragma unroll
      for (int off = 32; off; off >>= 1) s += __shfl_xor(s, off, 64);
      outA[(size_t)(i0 + wave) * HH + lane] = v - m - logf(s);
    }
  }
}

extern "C" void kernel_launch(void* const* d_in, const int* in_sizes, int n_in,
                              void* d_out, int out_size, void* d_ws,
                              size_t ws_size, hipStream_t stream) {
  const float* x_init = (const float*)d_in[0];
  const float* adj1   = (const float*)d_in[2];  // adj/fully_connected unused
  const float* W1     = (const float*)d_in[4];
  const float* b1     = (const float*)d_in[5];
  const float* W2     = (const float*)d_in[6];
  const float* b2     = (const float*)d_in[7];
  const float* W3     = (const float*)d_in[8];
  const float* b3     = (const float*)d_in[9];
  float* out = (float*)d_out;

  float* ws = (float*)d_ws;
  float* t1 = ws;                 // [1536,64]
  float* A2 = ws + 1 * NN * HH;
  float* B2 = ws + 2 * NN * HH;
  float* A3 = ws + 3 * NN * HH;
  float* B3 = ws + 4 * NN * HH;

  k_xw1<<<NB, NT, 0, stream>>>(x_init, W1, t1);
  k_layer<0><<<NB, NT, 0, stream>>>(adj1, t1, nullptr, b1, W2, A2, B2);
  k_layer<1><<<NB, NT, 0, stream>>>(adj1, B2, A2, b2, W3, A3, B3);
  k_layer<2><<<NB, NT, 0, stream>>>(adj1, B3, A3, b3, nullptr, out, nullptr);
}

// Round 5
// 33.852 us; speedup vs baseline: 2.8654x; 1.2776x over previous
//
#include <hip/hip_runtime.h>
#include <cmath>

constexpr int NN   = 1536;   // nodes
constexpr int FF   = 512;    // in features
constexpr int HH   = 64;     // hidden
constexpr int RPB  = 16;     // rows per block (MFMA M)
constexpr int NB   = NN / RPB;   // 96 blocks
constexpr int NT   = 1024;   // 16 waves
constexpr int WAVES = NT / 64;
constexpr int KST  = NN / 32;    // 48 k-steps of 32
constexpr int KST1 = FF / 32;    // 16 k-steps for the x@W1 matmul

using f32x4  = __attribute__((ext_vector_type(4))) float;
using bf16x8 = __attribute__((ext_vector_type(8))) short;
typedef unsigned short u16;

__device__ __forceinline__ u16 f2bf(float f) {  // RNE fp32 -> bf16
  unsigned u = __builtin_bit_cast(unsigned, f);
  return (u16)((u + 0x7fffu + ((u >> 16) & 1u)) >> 16);
}

// Tile conventions (consistent k-map for A and B => correct regardless of HW k-order):
//  A-tile (16 rows x 32 k): halfword idx = kstep*512 + ((k&31)>>3)*128 + r*8 + (k&7)
//    => lane l reads 16B at lane*16: row = l&15, k = 8*(l>>4) + e
//  B-tile (32 k x 16 cols): idx = (kstep*4 + c/16)*512 + ((k&31)>>3)*128 + (c&15)*8 + (k&7)
//    => lane l reads 16B: col = l&15, k = 8*(l>>4) + e
//  C/D (m89-verified): col = lane&15, row = (lane>>4)*4 + reg

// k_pre: pack adj -> adjT (bf16 A-tiles), deg = rowsum(adj),
//        t1 = x @ W1 via MFMA -> t1T (bf16 B-tiles)
__global__ __launch_bounds__(NT, 4) void k_pre(
    const float* __restrict__ x, const float* __restrict__ adj,
    const float* __restrict__ W1,
    u16* __restrict__ adjT, u16* __restrict__ t1T, float* __restrict__ deg) {
  __shared__ u16 Al[KST1 * 512];       // 16 KB  x rows as A-tiles
  __shared__ u16 Bl[KST1 * 4 * 512];   // 64 KB  W1 as B-tiles
  __shared__ u16 Jl[KST * 512];        // 48 KB  adj slab as A-tiles
  __shared__ float red[4][4][16][16];  // 16 KB
  const int tid = threadIdx.x, lane = tid & 63, wave = tid >> 6;
  const int i0 = blockIdx.x * RPB;

  // pack x rows -> Al (thread: row tid>>6, 8 consecutive k)
  {
    int i = tid >> 6, j0 = (tid & 63) * 8;
    const float* src = x + (size_t)(i0 + i) * FF + j0;
    bf16x8 v;
#pragma unroll
    for (int jj = 0; jj < 8; ++jj) v[jj] = (short)f2bf(src[jj]);
    *(bf16x8*)&Al[(j0 >> 5) * 512 + ((j0 & 31) >> 3) * 128 + i * 8] = v;
  }
  // pack W1 -> Bl (thread: one k-row, 32 cols)
  {
    int k = tid >> 1, c0 = (tid & 1) * 32;
    const float* src = W1 + (size_t)k * HH + c0;
    int base = (k >> 5) * 4 * 512 + ((k & 31) >> 3) * 128 + (k & 7);
    for (int cc = 0; cc < 32; ++cc) {
      int c = c0 + cc;
      Bl[base + (c >> 4) * 512 + (c & 15) * 8] = f2bf(src[cc]);
    }
  }
  // pack adj slab -> Jl (+ deg). thread: row tid>>6, 24 consecutive k (3x b128)
  {
    int i = tid >> 6, j0 = (tid & 63) * 24;
    const float* src = adj + (size_t)(i0 + i) * NN + j0;
    float dsum = 0.f;
#pragma unroll
    for (int g = 0; g < 3; ++g) {
      bf16x8 v;
#pragma unroll
      for (int jj = 0; jj < 8; ++jj) {
        float f = src[g * 8 + jj];
        dsum += f;
        v[jj] = (short)f2bf(f);
      }
      int k = j0 + g * 8;
      *(bf16x8*)&Jl[(k >> 5) * 512 + ((k & 31) >> 3) * 128 + i * 8] = v;
    }
#pragma unroll
    for (int off = 32; off; off >>= 1) dsum += __shfl_xor(dsum, off, 64);
    if ((tid & 63) == 0) deg[i0 + i] = dsum;
  }
  __syncthreads();

  // Jl -> adjT global (48 KB linear)
  {
    const float4* srcv = (const float4*)Jl;
    float4* dstv = (float4*)(adjT + (size_t)blockIdx.x * KST * 512);
#pragma unroll
    for (int s = 0; s < 3; ++s) dstv[tid + s * NT] = srcv[tid + s * NT];
  }
  // MFMA: t1 = x @ W1. wave = (ks 0..3, cg 0..3); 4 k-steps each
  {
    const int ks = wave >> 2, cg = wave & 3;
    f32x4 acc = {0.f, 0.f, 0.f, 0.f};
#pragma unroll
    for (int s = 0; s < 4; ++s) {
      int t = ks * 4 + s;
      bf16x8 a = *(const bf16x8*)&Al[t * 512 + lane * 8];
      bf16x8 b = *(const bf16x8*)&Bl[(t * 4 + cg) * 512 + lane * 8];
      acc = __builtin_amdgcn_mfma_f32_16x16x32_bf16(a, b, acc, 0, 0, 0);
    }
#pragma unroll
    for (int q = 0; q < 4; ++q)
      red[ks][cg][(lane >> 4) * 4 + q][lane & 15] = acc[q];
  }
  __syncthreads();
  // combine 4 k-segments, pack t1 -> t1T (B-tiles, k = node index)
  {
    int r = tid >> 6, c = tid & 63;
    float v = red[0][c >> 4][r][c & 15] + red[1][c >> 4][r][c & 15] +
              red[2][c >> 4][r][c & 15] + red[3][c >> 4][r][c & 15];
    int k = i0 + r;
    t1T[((k >> 5) * 4 + (c >> 4)) * 512 + ((k & 31) >> 3) * 128 +
        (c & 15) * 8 + (k & 7)] = f2bf(v);
  }
}

// k_layer: y = adj @ T (MFMA, frags straight from packed global, no LDS staging)
// MODE 0: x = relu(y + b);            outA = x@Wn[:64] (fp32), outBT = x@Wn[64:] (bf16 tiles)
// MODE 1: x = elu(Ain*deg + y + b);   outA/outBT as above
// MODE 2: x = Ain*deg + y + b;        out = log_softmax(x) rows
template <int MODE>
__global__ __launch_bounds__(NT, 4) void k_layer(
    const u16* __restrict__ adjT, const u16* __restrict__ TT,
    const float* __restrict__ Ain, const float* __restrict__ deg,
    const float* __restrict__ bias, const float* __restrict__ Wn,
    float* __restrict__ outA, u16* __restrict__ outBT,
    float* __restrict__ out) {
  __shared__ float red[WAVES][4][16][16];  // 64 KB
  __shared__ float xloc[16][HH];           // 4 KB
  __shared__ float Wl[2 * HH * HH];        // 32 KB
  const int tid = threadIdx.x, lane = tid & 63, wave = tid >> 6;
  const int i0 = blockIdx.x * RPB;

  if (MODE < 2) {
    const float4* src = (const float4*)Wn;
    float4* dst = (float4*)Wl;
    for (int idx = tid; idx < 2 * HH * HH / 4; idx += NT) dst[idx] = src[idx];
  }

  // K-loop: wave w covers k-steps w*3..w*3+2, all 4 col-groups.
  // 15 independent coalesced b128 loads, then 12 MFMAs.
  const u16* ja = adjT + (size_t)blockIdx.x * KST * 512;
  bf16x8 a[3], b[3][4];
#pragma unroll
  for (int s = 0; s < 3; ++s) {
    int kstep = wave * 3 + s;
    a[s] = *(const bf16x8*)(ja + kstep * 512 + lane * 8);
#pragma unroll
    for (int cg = 0; cg < 4; ++cg)
      b[s][cg] = *(const bf16x8*)(TT + (size_t)(kstep * 4 + cg) * 512 + lane * 8);
  }
  f32x4 acc[4] = {{0,0,0,0},{0,0,0,0},{0,0,0,0},{0,0,0,0}};
#pragma unroll
  for (int s = 0; s < 3; ++s)
#pragma unroll
    for (int cg = 0; cg < 4; ++cg)
      acc[cg] = __builtin_amdgcn_mfma_f32_16x16x32_bf16(a[s], b[s][cg], acc[cg], 0, 0, 0);
#pragma unroll
  for (int cg = 0; cg < 4; ++cg)
#pragma unroll
    for (int q = 0; q < 4; ++q)
      red[wave][cg][(lane >> 4) * 4 + q][lane & 15] = acc[cg][q];
  __syncthreads();

  // combine 16 k-segments + bias + deg-term + activation
  {
    int r = tid >> 6, c = tid & 63;
    float v = bias[c];
#pragma unroll
    for (int w = 0; w < WAVES; ++w) v += red[w][c >> 4][r][c & 15];
    if (MODE >= 1) v += Ain[(size_t)(i0 + r) * HH + c] * deg[i0 + r];
    if (MODE == 0) v = fmaxf(v, 0.f);
    if (MODE == 1) v = v > 0.f ? v : expm1f(v);
    xloc[r][c] = v;
  }
  __syncthreads();

  if (MODE < 2) {
    // A_next = x @ Wn[:64] (fp32), B_next = x @ Wn[64:] (bf16 B-tiles)
#pragma unroll
    for (int t = 0; t < 2; ++t) {
      int idx = tid + t * NT;
      int r = idx >> 7, cc = idx & 127, half = cc >> 6, col = cc & 63;
      float sacc = 0.f;
#pragma unroll
      for (int k = 0; k < HH; ++k)
        sacc = fmaf(xloc[r][k], Wl[(half * HH + k) * HH + col], sacc);
      if (half == 0) {
        outA[(size_t)(i0 + r) * HH + col] = sacc;
      } else {
        int kk = i0 + r;
        outBT[((kk >> 5) * 4 + (col >> 4)) * 512 + ((kk & 31) >> 3) * 128 +
              (col & 15) * 8 + (kk & 7)] = f2bf(sacc);
      }
    }
  } else {
    // log_softmax per row: wave w owns row w (16 rows, 16 waves)
    int r = wave;
    float v = xloc[r][lane];
    float m = v;
#pragma unroll
    for (int off = 32; off; off >>= 1) m = fmaxf(m, __shfl_xor(m, off, 64));
    float e = expf(v - m);
    float ssum = e;
#pragma unroll
    for (int off = 32; off; off >>= 1) ssum += __shfl_xor(ssum, off, 64);
    out[(size_t)(i0 + r) * HH + lane] = v - m - logf(ssum);
  }
}

extern "C" void kernel_launch(void* const* d_in, const int* in_sizes, int n_in,
                              void* d_out, int out_size, void* d_ws,
                              size_t ws_size, hipStream_t stream) {
  const float* x   = (const float*)d_in[0];
  const float* adj = (const float*)d_in[2];  // adj1; d_in[1]/[3] are dead inputs
  const float* W1  = (const float*)d_in[4];
  const float* b1  = (const float*)d_in[5];
  const float* W2  = (const float*)d_in[6];
  const float* b2  = (const float*)d_in[7];
  const float* W3  = (const float*)d_in[8];
  const float* b3  = (const float*)d_in[9];
  float* out = (float*)d_out;

  char* ws = (char*)d_ws;
  u16* adjT = (u16*)ws;                  // 96*48*1024 B = 4,718,592
  u16* t1T  = (u16*)(ws + 4718592);      // 196,608 B each
  u16* B2T  = (u16*)(ws + 4915200);
  u16* B3T  = (u16*)(ws + 5111808);
  float* A2 = (float*)(ws + 5308416);    // 393,216 B each
  float* A3 = (float*)(ws + 5701632);
  float* dg = (float*)(ws + 6094848);    // 6,144 B

  k_pre<<<NB, NT, 0, stream>>>(x, adj, W1, adjT, t1T, dg);
  k_layer<0><<<NB, NT, 0, stream>>>(adjT, t1T, nullptr, dg, b1, W2, A2, B2T, nullptr);
  k_layer<1><<<NB, NT, 0, stream>>>(adjT, B2T, A2, dg, b2, W3, A3, B3T, nullptr);
  k_layer<2><<<NB, NT, 0, stream>>>(adjT, B3T, A3, dg, b3, nullptr, nullptr, nullptr, out);
}